// Round 7
// baseline (212.349 us; speedup 1.0000x reference)
//
#include <hip/hip_runtime.h>

#define Bb 4
#define Nn 4096
#define Dd 256
#define Hh 4
#define HDd 64
#define FFf 512
#define MT 16384  // B*N

typedef __attribute__((ext_vector_type(8))) short short8;
typedef __attribute__((ext_vector_type(4))) float f32x4;
typedef __attribute__((ext_vector_type(16))) float f32x16;
typedef unsigned short u16;
typedef unsigned int u32;
typedef __attribute__((ext_vector_type(4))) u32 u32x4;

typedef __attribute__((address_space(1))) const void glb_src;
typedef __attribute__((address_space(3))) void lds_dst;

__device__ __forceinline__ void gload_lds16(const void* g, void* l) {
    __builtin_amdgcn_global_load_lds((glb_src*)g, (lds_dst*)l, 16, 0, 0);
}

__device__ __forceinline__ u16 f2bf(float f) {
    union { float f; u32 i; } v; v.f = f;
    u32 r = v.i + 0x7FFFu + ((v.i >> 16) & 1u);
    return (u16)(r >> 16);
}

__device__ __forceinline__ short8 ld8(const u16* p) {
    return *(const short8*)p;
}

// v_permlane32_swap: a' = [a.lo, b.lo], b' = [a.hi, b.hi]
__device__ __forceinline__ void pl32swap(u32& a, u32& b) {
    asm("v_permlane32_swap_b32 %0, %1" : "+v"(a), "+v"(b));
}
__device__ __forceinline__ float xhalf_max(float x) {
    u32 a = __float_as_uint(x), b = a;
    pl32swap(a, b);
    return fmaxf(__uint_as_float(a), __uint_as_float(b));
}
__device__ __forceinline__ u32 cvtpk(float lo, float hi) {
    u32 r;
    asm("v_cvt_pk_bf16_f32 %0, %1, %2" : "=v"(r) : "v"(lo), "v"(hi));
    return r;
}
__device__ __forceinline__ float fexp2(float x) {
    float r;
    asm("v_exp_f32 %0, %1" : "=v"(r) : "v"(x));
    return r;
}
__device__ __forceinline__ float max3f(float a, float b, float c) {
    float r;
    asm("v_max3_f32 %0, %1, %2, %3" : "=v"(r) : "v"(a), "v"(b), "v"(c));
    return r;
}

#define QSCALE 0.18033610062f  /* 0.125 * log2(e) */
#define LOG2E  1.44269504089f

// ---------------- weight prep: transpose + bf16 cast + imp pack ----------------
__global__ __launch_bounds__(256) void prep_kernel(
        const float* __restrict__ Wq, const float* __restrict__ Wk,
        const float* __restrict__ Wv, const float* __restrict__ Wo,
        const float* __restrict__ W1, const float* __restrict__ W2,
        const float* __restrict__ imp,
        u16* __restrict__ WqkvT, u16* __restrict__ WoT,
        u16* __restrict__ W1T, u16* __restrict__ W2T,
        u32* __restrict__ impPk) {
    int e = blockIdx.x * 256 + threadIdx.x;
    if (e < 196608) {                    // 768*256
        int c = e >> 8, k = e & 255;
        int mat = c >> 8;                // 0=q,1=k,2=v
        int cc = c & 255;
        const float* W = (mat == 0) ? Wq : ((mat == 1) ? Wk : Wv);
        WqkvT[(size_t)c * 256 + k] = f2bf(W[k * 256 + cc]);
    } else if (e < 262144) {
        int i = e - 196608; int n = i >> 8, k = i & 255;
        WoT[n * 256 + k] = f2bf(Wo[k * 256 + n]);
    } else if (e < 393216) {
        int i = e - 262144; int n = i >> 8, k = i & 255;
        W1T[n * 256 + k] = f2bf(W1[k * 512 + n]);
    } else if (e < 524288) {
        int i = e - 393216; int n = i >> 9, k = i & 511;
        W2T[n * 512 + k] = f2bf(W2[k * 256 + n]);
    } else {
        int i = e - 524288;              // 0..16383 = B*N importance entries
        float ivs = imp[i] * LOG2E;
        u16 ih = f2bf(ivs);
        float rem = ivs - __uint_as_float(((u32)ih) << 16);
        u16 il = f2bf(rem);
        impPk[i] = ((u32)il << 16) | ih;
    }
}

// ---------------- LayerNorm ----------------
__global__ __launch_bounds__(256) void ln_kernel(const float* __restrict__ x,
        const float* __restrict__ w, const float* __restrict__ bia,
        u16* __restrict__ out) {
    int lane = threadIdx.x & 63;
    int row = blockIdx.x * 4 + (threadIdx.x >> 6);
    const float* xr = x + (size_t)row * Dd;
    float4 v = *(const float4*)(xr + lane * 4);
    float s = v.x + v.y + v.z + v.w;
    float s2 = v.x * v.x + v.y * v.y + v.z * v.z + v.w * v.w;
    #pragma unroll
    for (int off = 1; off < 64; off <<= 1) {
        s  += __shfl_xor(s, off);
        s2 += __shfl_xor(s2, off);
    }
    float mu = s * (1.0f / Dd);
    float var = s2 * (1.0f / Dd) - mu * mu;
    float rstd = rsqrtf(var + 1e-5f);
    float4 wv = *(const float4*)(w + lane * 4);
    float4 bv = *(const float4*)(bia + lane * 4);
    ushort4 ov;
    ov.x = f2bf((v.x - mu) * rstd * wv.x + bv.x);
    ov.y = f2bf((v.y - mu) * rstd * wv.y + bv.y);
    ov.z = f2bf((v.z - mu) * rstd * wv.z + bv.z);
    ov.w = f2bf((v.w - mu) * rstd * wv.w + bv.w);
    *(ushort4*)(out + (size_t)row * Dd + lane * 4) = ov;
}

// ---------------- GEMM: A[M,K] bf16 x BT[N,K] bf16 -> epilogue ----------------
// Staging via global_load_lds w16: linear LDS dest, inverse-swizzled source.
template<int MODE, int KD>
__global__ __launch_bounds__(256) void gemm_bt(
        const u16* __restrict__ A, const u16* __restrict__ BT,
        const float* __restrict__ bias0, const float* __restrict__ bias1,
        const float* __restrict__ bias2,
        const float* __restrict__ resid, float* __restrict__ outf,
        u16* __restrict__ o0, u16* __restrict__ o1, u16* __restrict__ o2) {
    __shared__ u16 Asl[128 * 32];
    __shared__ u16 Bsl[128 * 32];
    int lane = threadIdx.x & 63;
    int wv = threadIdx.x >> 6;
    int wm = wv >> 1, wn = wv & 1;
    int m0 = blockIdx.y * 128, n0 = blockIdx.x * 128;
    f32x4 zz; zz[0] = 0.f; zz[1] = 0.f; zz[2] = 0.f; zz[3] = 0.f;
    f32x4 acc[4][4];
    #pragma unroll
    for (int i = 0; i < 4; ++i)
        #pragma unroll
        for (int j = 0; j < 4; ++j) acc[i][j] = zz;

    for (int kt = 0; kt < KD; kt += 32) {
        __syncthreads();
        #pragma unroll
        for (int i = 0; i < 2; ++i) {
            int chunk = threadIdx.x + i * 256;
            int row = chunk >> 2, c16 = chunk & 3;
            int srcc = (c16 ^ (row & 3)) * 8;     // inverse swizzle on source
            char* adst = (char*)Asl + wv * 1024 + i * 4096;  // wave-uniform base
            char* bdst = (char*)Bsl + wv * 1024 + i * 4096;
            gload_lds16(A  + (size_t)(m0 + row) * KD + kt + srcc, adst);
            gload_lds16(BT + (size_t)(n0 + row) * KD + kt + srcc, bdst);
        }
        __syncthreads();
        short8 af[4], bfr[4];
        #pragma unroll
        for (int t = 0; t < 4; ++t) {
            int arow = wm * 64 + t * 16 + (lane & 15);
            af[t]  = ld8(Asl + arow * 32 + (((lane >> 4) * 8) ^ ((arow & 3) * 8)));
            int brow = wn * 64 + t * 16 + (lane & 15);
            bfr[t] = ld8(Bsl + brow * 32 + (((lane >> 4) * 8) ^ ((brow & 3) * 8)));
        }
        #pragma unroll
        for (int mt = 0; mt < 4; ++mt)
            #pragma unroll
            for (int nt = 0; nt < 4; ++nt)
                acc[mt][nt] = __builtin_amdgcn_mfma_f32_16x16x32_bf16(af[mt], bfr[nt], acc[mt][nt], 0, 0, 0);
    }

    #pragma unroll
    for (int mt = 0; mt < 4; ++mt) {
        #pragma unroll
        for (int nt = 0; nt < 4; ++nt) {
            #pragma unroll
            for (int r = 0; r < 4; ++r) {
                int row = m0 + wm * 64 + mt * 16 + (lane >> 4) * 4 + r;
                int col = n0 + wn * 64 + nt * 16 + (lane & 15);
                float v = acc[mt][nt][r];
                if (MODE == 0) {
                    int mat = col >> 8;
                    int cc = col & 255;
                    int hh = cc >> 6, dd = cc & 63;
                    int bbi = row >> 12, nni = row & 4095;
                    int bh = bbi * Hh + hh;
                    // q pre-scaled by 0.125*log2(e) for exp2-domain flash attention
                    if (mat == 0)      o0[((size_t)bh * Nn + nni) * HDd + dd] = f2bf((v + bias0[cc]) * QSCALE);
                    else if (mat == 1) o1[((size_t)bh * Nn + nni) * HDd + dd] = f2bf(v + bias1[cc]);
                    else               o2[((size_t)bh * HDd + dd) * Nn + nni] = f2bf(v + bias2[cc]);
                } else if (MODE == 1) {
                    outf[(size_t)row * Dd + col] = resid[(size_t)row * Dd + col] + v + bias0[col];
                } else if (MODE == 2) {
                    float xg = v + bias0[col];
                    float g = 0.5f * xg * (1.0f + erff(xg * 0.70710678118654752f));
                    o0[(size_t)row * FFf + col] = f2bf(g);
                } else {
                    outf[(size_t)row * Dd + col] = resid[(size_t)row * Dd + col] + v + bias0[col];
                }
            }
        }
    }
}

// ---------------- Flash attention, KV-split x4, swapped-operand 32x32x16 ----------------
// grid: 4 quarters x 16 bh x 32 q-tiles(128). 4 waves x 32 q-rows. Each block
// processes 1024 keys; writes unnormalized ctx^T partials (bf16) + m,l (f32).
// Softmax: R5-proven defer-max online form (exp2 domain).
__global__ __launch_bounds__(256, 4) void attn_kernel(
        const u16* __restrict__ Qb, const u16* __restrict__ Kb,
        const u16* __restrict__ VTb, const u32* __restrict__ impPk,
        u16* __restrict__ pc, float* __restrict__ pm, float* __restrict__ pl) {
    __shared__ u16 Klds[2][64 * 64];
    __shared__ u16 Vlds[2][64 * 64];
    int lane = threadIdx.x & 63;
    int wv = threadIdx.x >> 6;
    int kvq = blockIdx.x >> 9;           // 0..3
    int bh = (blockIdx.x >> 5) & 15;
    int qt = blockIdx.x & 31;
    int bbi = bh >> 2;
    int qrow0 = qt * 128 + wv * 32;
    int q = lane & 31;
    int hf = lane >> 5;
    int key0 = kvq * 1024;
    int pg = kvq * 16 + bh;

    // Q B-frags (hoisted)
    short8 qf[4];
    #pragma unroll
    for (int ks = 0; ks < 4; ++ks)
        qf[ks] = ld8(Qb + ((size_t)bh * Nn + qrow0 + q) * HDd + ks * 16 + hf * 8);

    // B-frag with ones at k=0,1 (importance augmentation)
    short8 onef = (short8)0;
    if (hf == 0) { onef[0] = (short)0x3F80; onef[1] = (short)0x3F80; }
    // all-ones A-frag (l accumulation via MFMA row-sum)
    short8 aone;
    #pragma unroll
    for (int j = 0; j < 8; ++j) aone[j] = (short)0x3F80;

    // staging: lane covers LDS row base+(l>>3), slot l&7; source pre-swizzled
    int sr = lane >> 3;
    int sc = lane & 7;
    int swz = (sc ^ sr) * 8;
    const u16* kp = Kb + ((size_t)bh * Nn + key0 + wv * 16 + sr) * HDd + swz;
    const u16* vp = VTb + ((size_t)bh * HDd + wv * 16 + sr) * Nn + key0 + swz;
    size_t ib = (size_t)bbi * Nn;

    gload_lds16(kp,           (char*)Klds[0] + wv * 2048);
    gload_lds16(kp + 8 * HDd, (char*)Klds[0] + wv * 2048 + 1024);
    gload_lds16(vp,           (char*)Vlds[0] + wv * 2048);
    gload_lds16(vp + 8 * Nn,  (char*)Vlds[0] + wv * 2048 + 1024);
    kp += 64 * HDd; vp += 64;
    u32 npk0 = impPk[ib + key0 + q], npk1 = impPk[ib + key0 + 32 + q];

    f32x16 ctx[2], lacc;
    #pragma unroll
    for (int r = 0; r < 16; ++r) { ctx[0][r] = 0.f; ctx[1][r] = 0.f; lacc[r] = 0.f; }
    float m = -__builtin_inff();

    int cur = 0;
    for (int t = 0; t < 16; ++t) {
        __syncthreads();   // buf[cur] ready; buf[cur^1] free
        u32 pk0 = npk0, pk1 = npk1;
        if (t < 15) {
            gload_lds16(kp,           (char*)Klds[cur ^ 1] + wv * 2048);
            gload_lds16(kp + 8 * HDd, (char*)Klds[cur ^ 1] + wv * 2048 + 1024);
            gload_lds16(vp,           (char*)Vlds[cur ^ 1] + wv * 2048);
            gload_lds16(vp + 8 * Nn,  (char*)Vlds[cur ^ 1] + wv * 2048 + 1024);
            kp += 64 * HDd; vp += 64;
            npk0 = impPk[ib + key0 + t * 64 + 64 + q];
            npk1 = impPk[ib + key0 + t * 64 + 96 + q];
        }
        const u16* Kc = Klds[cur];
        const u16* Vc = Vlds[cur];

        // ---- QK^T both 32-key halves interleaved ----
        f32x16 s0, s1;
        #pragma unroll
        for (int r = 0; r < 16; ++r) { s0[r] = 0.f; s1[r] = 0.f; }
        __builtin_amdgcn_s_setprio(1);
        #pragma unroll
        for (int ks = 0; ks < 4; ++ks) {
            short8 kf0 = ld8(Kc + q * 64 + (((ks * 2 + hf) ^ (q & 7)) * 8));
            short8 kf1 = ld8(Kc + (32 + q) * 64 + (((ks * 2 + hf) ^ (q & 7)) * 8));
            s0 = __builtin_amdgcn_mfma_f32_32x32x16_bf16(kf0, qf[ks], s0, 0, 0, 0);
            s1 = __builtin_amdgcn_mfma_f32_32x32x16_bf16(kf1, qf[ks], s1, 0, 0, 0);
        }
        short8 af0 = (short8)0, af1 = (short8)0;
        if (hf == 0) {
            af0[0] = (short)(pk0 & 0xFFFFu); af0[1] = (short)(pk0 >> 16);
            af1[0] = (short)(pk1 & 0xFFFFu); af1[1] = (short)(pk1 >> 16);
        }
        s0 = __builtin_amdgcn_mfma_f32_32x32x16_bf16(af0, onef, s0, 0, 0, 0);
        s1 = __builtin_amdgcn_mfma_f32_32x32x16_bf16(af1, onef, s1, 0, 0, 0);
        __builtin_amdgcn_s_setprio(0);

        // ---- merged online softmax over 32 scores (exp2 domain) ----
        float a0 = max3f(s0[0], s0[1], s0[2]);
        float a1 = max3f(s0[3], s0[4], s0[5]);
        float a2 = max3f(s0[6], s0[7], s0[8]);
        float a3 = max3f(s0[9], s0[10], s0[11]);
        float a4 = max3f(s0[12], s0[13], s0[14]);
        float b0 = max3f(s1[0], s1[1], s1[2]);
        float b1 = max3f(s1[3], s1[4], s1[5]);
        float b2 = max3f(s1[6], s1[7], s1[8]);
        float b3 = max3f(s1[9], s1[10], s1[11]);
        float b4 = max3f(s1[12], s1[13], s1[14]);
        float c0 = max3f(a0, a1, a2);
        float c1 = max3f(a3, a4, s0[15]);
        float c2 = max3f(b0, b1, b2);
        float c3 = max3f(b3, b4, s1[15]);
        float tm = fmaxf(max3f(c0, c1, c2), c3);
        tm = xhalf_max(tm);
        bool nore = __all(tm <= m + 8.0f);
        if (!nore) {
            float nm = fmaxf(m, tm);
            float al = fexp2(m - nm);
            lacc[0] *= al;
            #pragma unroll
            for (int r = 0; r < 16; ++r) { ctx[0][r] *= al; ctx[1][r] *= al; }
            m = nm;
        }
        #pragma unroll
        for (int r = 0; r < 16; ++r) { s0[r] = fexp2(s0[r] - m); s1[r] = fexp2(s1[r] - m); }

        // ---- P -> bf16 B-frags in-register ----
        u32 w0[8], w1[8];
        #pragma unroll
        for (int j = 0; j < 8; ++j) {
            w0[j] = cvtpk(s0[2 * j], s0[2 * j + 1]);
            w1[j] = cvtpk(s1[2 * j], s1[2 * j + 1]);
        }
        pl32swap(w0[0], w0[2]); pl32swap(w0[1], w0[3]);
        pl32swap(w0[4], w0[6]); pl32swap(w0[5], w0[7]);
        pl32swap(w1[0], w1[2]); pl32swap(w1[1], w1[3]);
        pl32swap(w1[4], w1[6]); pl32swap(w1[5], w1[7]);
        u32x4 t00; t00[0] = w0[0]; t00[1] = w0[1]; t00[2] = w0[2]; t00[3] = w0[3];
        u32x4 t01; t01[0] = w0[4]; t01[1] = w0[5]; t01[2] = w0[6]; t01[3] = w0[7];
        u32x4 t10; t10[0] = w1[0]; t10[1] = w1[1]; t10[2] = w1[2]; t10[3] = w1[3];
        u32x4 t11; t11[0] = w1[4]; t11[1] = w1[5]; t11[2] = w1[6]; t11[3] = w1[7];
        short8 pf00 = __builtin_bit_cast(short8, t00);
        short8 pf01 = __builtin_bit_cast(short8, t01);
        short8 pf10 = __builtin_bit_cast(short8, t10);
        short8 pf11 = __builtin_bit_cast(short8, t11);

        // ---- PV + l-accumulation ----
        __builtin_amdgcn_s_setprio(1);
        lacc = __builtin_amdgcn_mfma_f32_32x32x16_bf16(aone, pf00, lacc, 0, 0, 0);
        lacc = __builtin_amdgcn_mfma_f32_32x32x16_bf16(aone, pf01, lacc, 0, 0, 0);
        lacc = __builtin_amdgcn_mfma_f32_32x32x16_bf16(aone, pf10, lacc, 0, 0, 0);
        lacc = __builtin_amdgcn_mfma_f32_32x32x16_bf16(aone, pf11, lacc, 0, 0, 0);
        #pragma unroll
        for (int dt = 0; dt < 2; ++dt) {
            int vrow = dt * 32 + q;
            const u16* vb = Vc + vrow * 64;
            int sw = vrow & 7;
            short8 vf;
            vf = ld8(vb + (((0 + hf) ^ sw) * 8));
            ctx[dt] = __builtin_amdgcn_mfma_f32_32x32x16_bf16(vf, pf00, ctx[dt], 0, 0, 0);
            vf = ld8(vb + (((2 + hf) ^ sw) * 8));
            ctx[dt] = __builtin_amdgcn_mfma_f32_32x32x16_bf16(vf, pf01, ctx[dt], 0, 0, 0);
            vf = ld8(vb + (((4 + hf) ^ sw) * 8));
            ctx[dt] = __builtin_amdgcn_mfma_f32_32x32x16_bf16(vf, pf10, ctx[dt], 0, 0, 0);
            vf = ld8(vb + (((6 + hf) ^ sw) * 8));
            ctx[dt] = __builtin_amdgcn_mfma_f32_32x32x16_bf16(vf, pf11, ctx[dt], 0, 0, 0);
        }
        __builtin_amdgcn_s_setprio(0);
        cur ^= 1;
    }

    // ---- epilogue: write unnormalized partials ----
    int qg = qrow0 + q;
    if (hf == 0) {
        pm[(size_t)pg * Nn + qg] = m;
        pl[(size_t)pg * Nn + qg] = lacc[0];
    }
    #pragma unroll
    for (int dt = 0; dt < 2; ++dt) {
        #pragma unroll
        for (int r = 0; r < 16; ++r) {
            int d = dt * 32 + (r & 3) + 8 * (r >> 2) + 4 * hf;
            pc[((size_t)pg * 64 + d) * Nn + qg] = f2bf(ctx[dt][r]);
        }
    }
}

// ---------------- merge: combine 4 KV-quarters, transpose to ctx layout ----------------
__global__ __launch_bounds__(256) void merge_kernel(
        const u16* __restrict__ pc, const float* __restrict__ pm,
        const float* __restrict__ pl, u16* __restrict__ ctxOut) {
    __shared__ float trans[64][65];
    __shared__ float fw[4][64];
    int bh = blockIdx.x >> 6;
    int q0 = (blockIdx.x & 63) * 64;
    int t = threadIdx.x;
    if (t < 64) {
        int qg = q0 + t;
        float m0 = pm[(size_t)(bh) * Nn + qg];
        float m1 = pm[(size_t)(16 + bh) * Nn + qg];
        float m2 = pm[(size_t)(32 + bh) * Nn + qg];
        float m3 = pm[(size_t)(48 + bh) * Nn + qg];
        float M = fmaxf(fmaxf(m0, m1), fmaxf(m2, m3));
        float w0 = fexp2(m0 - M), w1 = fexp2(m1 - M);
        float w2 = fexp2(m2 - M), w3 = fexp2(m3 - M);
        float l = pl[(size_t)(bh) * Nn + qg] * w0
                + pl[(size_t)(16 + bh) * Nn + qg] * w1
                + pl[(size_t)(32 + bh) * Nn + qg] * w2
                + pl[(size_t)(48 + bh) * Nn + qg] * w3;
        float inv = 1.0f / l;
        fw[0][t] = w0 * inv; fw[1][t] = w1 * inv;
        fw[2][t] = w2 * inv; fw[3][t] = w3 * inv;
    }
    __syncthreads();
    int wv = t >> 6, lane = t & 63;
    #pragma unroll
    for (int i = 0; i < 16; ++i) {
        int d = wv * 16 + i;
        float acc = 0.f;
        #pragma unroll
        for (int j = 0; j < 4; ++j) {
            float c = __uint_as_float((u32)pc[((size_t)(j * 16 + bh) * 64 + d) * Nn + q0 + lane] << 16);
            acc += c * fw[j][lane];
        }
        trans[lane][d] = acc;
    }
    __syncthreads();
    int q = t >> 2, dg = t & 3;
    int b = bh >> 2, h = bh & 3;
    const float* tr = &trans[q][dg * 16];
    uint4 pa, pb;
    pa.x = cvtpk(tr[0], tr[1]);  pa.y = cvtpk(tr[2], tr[3]);
    pa.z = cvtpk(tr[4], tr[5]);  pa.w = cvtpk(tr[6], tr[7]);
    pb.x = cvtpk(tr[8], tr[9]);  pb.y = cvtpk(tr[10], tr[11]);
    pb.z = cvtpk(tr[12], tr[13]); pb.w = cvtpk(tr[14], tr[15]);
    u16* op = ctxOut + ((size_t)b * Nn + q0 + q) * Dd + h * 64 + dg * 16;
    *(uint4*)op = pa;
    *(uint4*)(op + 8) = pb;
}

extern "C" void kernel_launch(void* const* d_in, const int* in_sizes, int n_in,
                              void* d_out, int out_size, void* d_ws, size_t ws_size,
                              hipStream_t stream) {
    (void)in_sizes; (void)n_in; (void)out_size; (void)ws_size;
    const float* tokens     = (const float*)d_in[0];
    const float* importance = (const float*)d_in[1];
    const float* n1w = (const float*)d_in[2];
    const float* n1b = (const float*)d_in[3];
    const float* Wq  = (const float*)d_in[4];
    const float* bq  = (const float*)d_in[5];
    const float* Wk  = (const float*)d_in[6];
    const float* bk  = (const float*)d_in[7];
    const float* Wv  = (const float*)d_in[8];
    const float* bv  = (const float*)d_in[9];
    const float* Wo  = (const float*)d_in[10];
    const float* bo  = (const float*)d_in[11];
    const float* n2w = (const float*)d_in[12];
    const float* n2b = (const float*)d_in[13];
    const float* W1  = (const float*)d_in[14];
    const float* b1  = (const float*)d_in[15];
    const float* W2  = (const float*)d_in[16];
    const float* b2  = (const float*)d_in[17];
    float* out = (float*)d_out;

    char* ws = (char*)d_ws;
    const size_t MB = (size_t)1 << 20;
    // Sequential reuse (single stream): yln reuses xln (dead after QKV GEMM);
    // hbuf reuses qb+kb (dead after attn); x2 = d_out (dead until MODE 1).
    u16* xln   = (u16*)(ws);                    // 0..8MB   (later: yln)
    u16* qb    = (u16*)(ws + 8 * MB);           // 8..16MB  (later: hbuf lo)
    u16* kb    = (u16*)(ws + 16 * MB);          // 16..24MB (later: hbuf hi)
    u16* vT    = (u16*)(ws + 24 * MB);          // 24..32MB
    u16* ctx   = (u16*)(ws + 32 * MB);          // 32..40MB
    u16* pc    = (u16*)(ws + 40 * MB);          // 40..72MB [kvq*16+bh][64 d][4096 q]
    float* pm  = (float*)(ws + 72 * MB);        // 1MB
    float* pl  = (float*)(ws + 73 * MB);        // 1MB
    u16* WqkvT = (u16*)(ws + 74 * MB);          // 384KB
    u16* WoT   = (u16*)(ws + 74 * MB + 393216);
    u16* W1T   = (u16*)(ws + 74 * MB + 393216 + 131072);
    u16* W2T   = (u16*)(ws + 74 * MB + 393216 + 131072 + 262144);
    u32* impPk = (u32*)(ws + 74 * MB + 393216 + 131072 + 262144 + 262144);
    u16* yln   = xln;                           // reuse (xln dead after QKV)
    u16* hbuf  = qb;                            // reuse 16MB (qb+kb dead after attn)
    float* x2  = out;                           // reuse d_out as x2 scratch

    prep_kernel<<<2112, 256, 0, stream>>>(Wq, Wk, Wv, Wo, W1, W2, importance,
                                          WqkvT, WoT, W1T, W2T, impPk);
    ln_kernel<<<4096, 256, 0, stream>>>(tokens, n1w, n1b, xln);
    gemm_bt<0, 256><<<dim3(6, 128), 256, 0, stream>>>(xln, WqkvT, bq, bk, bv,
                                                      nullptr, nullptr, qb, kb, vT);
    attn_kernel<<<2048, 256, 0, stream>>>(qb, kb, vT, impPk, pc, pm, pl);
    merge_kernel<<<1024, 256, 0, stream>>>(pc, pm, pl, ctx);
    gemm_bt<1, 256><<<dim3(2, 128), 256, 0, stream>>>(ctx, WoT, bo, nullptr, nullptr,
                                                      tokens, x2, nullptr, nullptr, nullptr);
    ln_kernel<<<4096, 256, 0, stream>>>(x2, n2w, n2b, yln);
    gemm_bt<2, 256><<<dim3(4, 128), 256, 0, stream>>>(yln, W1T, b1, nullptr, nullptr,
                                                      nullptr, nullptr, hbuf, nullptr, nullptr);
    gemm_bt<3, 512><<<dim3(2, 128), 256, 0, stream>>>(hbuf, W2T, b2, nullptr, nullptr,
                                                      x2, out, nullptr, nullptr, nullptr);
}

// Round 8
// 210.754 us; speedup vs baseline: 1.0076x; 1.0076x over previous
//
#include <hip/hip_runtime.h>

#define Bb 4
#define Nn 4096
#define Dd 256
#define Hh 4
#define HDd 64
#define FFf 512
#define MT 16384  // B*N

typedef __attribute__((ext_vector_type(8))) short short8;
typedef __attribute__((ext_vector_type(4))) float f32x4;
typedef __attribute__((ext_vector_type(16))) float f32x16;
typedef unsigned short u16;
typedef unsigned int u32;
typedef __attribute__((ext_vector_type(4))) u32 u32x4;

typedef __attribute__((address_space(1))) const void glb_src;
typedef __attribute__((address_space(3))) void lds_dst;

__device__ __forceinline__ void gload_lds16(const void* g, void* l) {
    __builtin_amdgcn_global_load_lds((glb_src*)g, (lds_dst*)l, 16, 0, 0);
}

__device__ __forceinline__ u16 f2bf(float f) {
    union { float f; u32 i; } v; v.f = f;
    u32 r = v.i + 0x7FFFu + ((v.i >> 16) & 1u);
    return (u16)(r >> 16);
}

__device__ __forceinline__ short8 ld8(const u16* p) {
    return *(const short8*)p;
}

// v_permlane32_swap: a' = [a.lo, b.lo], b' = [a.hi, b.hi]
__device__ __forceinline__ void pl32swap(u32& a, u32& b) {
    asm("v_permlane32_swap_b32 %0, %1" : "+v"(a), "+v"(b));
}
__device__ __forceinline__ float xhalf_max(float x) {
    u32 a = __float_as_uint(x), b = a;
    pl32swap(a, b);
    return fmaxf(__uint_as_float(a), __uint_as_float(b));
}
__device__ __forceinline__ u32 cvtpk(float lo, float hi) {
    u32 r;
    asm("v_cvt_pk_bf16_f32 %0, %1, %2" : "=v"(r) : "v"(lo), "v"(hi));
    return r;
}
__device__ __forceinline__ float fexp2(float x) {
    float r;
    asm("v_exp_f32 %0, %1" : "=v"(r) : "v"(x));
    return r;
}
__device__ __forceinline__ float max3f(float a, float b, float c) {
    float r;
    asm("v_max3_f32 %0, %1, %2, %3" : "=v"(r) : "v"(a), "v"(b), "v"(c));
    return r;
}

#define QSCALE 0.18033610062f  /* 0.125 * log2(e) */
#define LOG2E  1.44269504089f

// ---------------- weight prep: transpose + bf16 cast + imp pack ----------------
__global__ __launch_bounds__(256) void prep_kernel(
        const float* __restrict__ Wq, const float* __restrict__ Wk,
        const float* __restrict__ Wv, const float* __restrict__ Wo,
        const float* __restrict__ W1, const float* __restrict__ W2,
        const float* __restrict__ imp,
        u16* __restrict__ WqkvT, u16* __restrict__ WoT,
        u16* __restrict__ W1T, u16* __restrict__ W2T,
        u32* __restrict__ impPk) {
    int e = blockIdx.x * 256 + threadIdx.x;
    if (e < 196608) {                    // 768*256
        int c = e >> 8, k = e & 255;
        int mat = c >> 8;                // 0=q,1=k,2=v
        int cc = c & 255;
        const float* W = (mat == 0) ? Wq : ((mat == 1) ? Wk : Wv);
        WqkvT[(size_t)c * 256 + k] = f2bf(W[k * 256 + cc]);
    } else if (e < 262144) {
        int i = e - 196608; int n = i >> 8, k = i & 255;
        WoT[n * 256 + k] = f2bf(Wo[k * 256 + n]);
    } else if (e < 393216) {
        int i = e - 262144; int n = i >> 8, k = i & 255;
        W1T[n * 256 + k] = f2bf(W1[k * 512 + n]);
    } else if (e < 524288) {
        int i = e - 393216; int n = i >> 9, k = i & 511;
        W2T[n * 512 + k] = f2bf(W2[k * 256 + n]);
    } else {
        int i = e - 524288;              // 0..16383 = B*N importance entries
        float ivs = imp[i] * LOG2E;
        u16 ih = f2bf(ivs);
        float rem = ivs - __uint_as_float(((u32)ih) << 16);
        u16 il = f2bf(rem);
        impPk[i] = ((u32)il << 16) | ih;
    }
}

// ---------------- LayerNorm ----------------
__global__ __launch_bounds__(256) void ln_kernel(const float* __restrict__ x,
        const float* __restrict__ w, const float* __restrict__ bia,
        u16* __restrict__ out) {
    int lane = threadIdx.x & 63;
    int row = blockIdx.x * 4 + (threadIdx.x >> 6);
    const float* xr = x + (size_t)row * Dd;
    float4 v = *(const float4*)(xr + lane * 4);
    float s = v.x + v.y + v.z + v.w;
    float s2 = v.x * v.x + v.y * v.y + v.z * v.z + v.w * v.w;
    #pragma unroll
    for (int off = 1; off < 64; off <<= 1) {
        s  += __shfl_xor(s, off);
        s2 += __shfl_xor(s2, off);
    }
    float mu = s * (1.0f / Dd);
    float var = s2 * (1.0f / Dd) - mu * mu;
    float rstd = rsqrtf(var + 1e-5f);
    float4 wv = *(const float4*)(w + lane * 4);
    float4 bv = *(const float4*)(bia + lane * 4);
    ushort4 ov;
    ov.x = f2bf((v.x - mu) * rstd * wv.x + bv.x);
    ov.y = f2bf((v.y - mu) * rstd * wv.y + bv.y);
    ov.z = f2bf((v.z - mu) * rstd * wv.z + bv.z);
    ov.w = f2bf((v.w - mu) * rstd * wv.w + bv.w);
    *(ushort4*)(out + (size_t)row * Dd + lane * 4) = ov;
}

// ---------------- GEMM: A[M,K] bf16 x BT[N,K] bf16 -> epilogue ----------------
// Staging via global_load_lds w16: linear LDS dest, inverse-swizzled source.
template<int MODE, int KD>
__global__ __launch_bounds__(256) void gemm_bt(
        const u16* __restrict__ A, const u16* __restrict__ BT,
        const float* __restrict__ bias0, const float* __restrict__ bias1,
        const float* __restrict__ bias2,
        const float* __restrict__ resid, float* __restrict__ outf,
        u16* __restrict__ o0, u16* __restrict__ o1, u16* __restrict__ o2) {
    __shared__ u16 Asl[128 * 32];
    __shared__ u16 Bsl[128 * 32];
    int lane = threadIdx.x & 63;
    int wv = threadIdx.x >> 6;
    int wm = wv >> 1, wn = wv & 1;
    int m0 = blockIdx.y * 128, n0 = blockIdx.x * 128;
    f32x4 zz; zz[0] = 0.f; zz[1] = 0.f; zz[2] = 0.f; zz[3] = 0.f;
    f32x4 acc[4][4];
    #pragma unroll
    for (int i = 0; i < 4; ++i)
        #pragma unroll
        for (int j = 0; j < 4; ++j) acc[i][j] = zz;

    for (int kt = 0; kt < KD; kt += 32) {
        __syncthreads();
        #pragma unroll
        for (int i = 0; i < 2; ++i) {
            int chunk = threadIdx.x + i * 256;
            int row = chunk >> 2, c16 = chunk & 3;
            int srcc = (c16 ^ (row & 3)) * 8;     // inverse swizzle on source
            char* adst = (char*)Asl + wv * 1024 + i * 4096;  // wave-uniform base
            char* bdst = (char*)Bsl + wv * 1024 + i * 4096;
            gload_lds16(A  + (size_t)(m0 + row) * KD + kt + srcc, adst);
            gload_lds16(BT + (size_t)(n0 + row) * KD + kt + srcc, bdst);
        }
        __syncthreads();
        short8 af[4], bfr[4];
        #pragma unroll
        for (int t = 0; t < 4; ++t) {
            int arow = wm * 64 + t * 16 + (lane & 15);
            af[t]  = ld8(Asl + arow * 32 + (((lane >> 4) * 8) ^ ((arow & 3) * 8)));
            int brow = wn * 64 + t * 16 + (lane & 15);
            bfr[t] = ld8(Bsl + brow * 32 + (((lane >> 4) * 8) ^ ((brow & 3) * 8)));
        }
        #pragma unroll
        for (int mt = 0; mt < 4; ++mt)
            #pragma unroll
            for (int nt = 0; nt < 4; ++nt)
                acc[mt][nt] = __builtin_amdgcn_mfma_f32_16x16x32_bf16(af[mt], bfr[nt], acc[mt][nt], 0, 0, 0);
    }

    #pragma unroll
    for (int mt = 0; mt < 4; ++mt) {
        #pragma unroll
        for (int nt = 0; nt < 4; ++nt) {
            #pragma unroll
            for (int r = 0; r < 4; ++r) {
                int row = m0 + wm * 64 + mt * 16 + (lane >> 4) * 4 + r;
                int col = n0 + wn * 64 + nt * 16 + (lane & 15);
                float v = acc[mt][nt][r];
                if (MODE == 0) {
                    int mat = col >> 8;
                    int cc = col & 255;
                    int hh = cc >> 6, dd = cc & 63;
                    int bbi = row >> 12, nni = row & 4095;
                    int bh = bbi * Hh + hh;
                    // q pre-scaled by 0.125*log2(e) for exp2-domain flash attention
                    if (mat == 0)      o0[((size_t)bh * Nn + nni) * HDd + dd] = f2bf((v + bias0[cc]) * QSCALE);
                    else if (mat == 1) o1[((size_t)bh * Nn + nni) * HDd + dd] = f2bf(v + bias1[cc]);
                    else               o2[((size_t)bh * HDd + dd) * Nn + nni] = f2bf(v + bias2[cc]);
                } else if (MODE == 1) {
                    outf[(size_t)row * Dd + col] = resid[(size_t)row * Dd + col] + v + bias0[col];
                } else if (MODE == 2) {
                    float xg = v + bias0[col];
                    float g = 0.5f * xg * (1.0f + erff(xg * 0.70710678118654752f));
                    o0[(size_t)row * FFf + col] = f2bf(g);
                } else {
                    outf[(size_t)row * Dd + col] = resid[(size_t)row * Dd + col] + v + bias0[col];
                }
            }
        }
    }
}

// ---------------- Flash attention, KV-split x2, swapped-operand 32x32x16 ----------------
// grid: 2 halves x 16 bh x 32 q-tiles(128). 4 waves x 32 q-rows. Each block
// processes 2048 keys; writes unnormalized ctx^T partials (bf16) + m,l (f32).
// R5-proven defer-max softmax; VALU trims: hoisted zero-C, u32-select af build.
__global__ __launch_bounds__(256, 4) void attn_kernel(
        const u16* __restrict__ Qb, const u16* __restrict__ Kb,
        const u16* __restrict__ VTb, const u32* __restrict__ impPk,
        u16* __restrict__ pc, float* __restrict__ pm, float* __restrict__ pl) {
    __shared__ u16 Klds[2][64 * 64];
    __shared__ u16 Vlds[2][64 * 64];
    int lane = threadIdx.x & 63;
    int wv = threadIdx.x >> 6;
    int kvh = blockIdx.x >> 9;
    int bh = (blockIdx.x >> 5) & 15;
    int qt = blockIdx.x & 31;
    int bbi = bh >> 2;
    int qrow0 = qt * 128 + wv * 32;
    int q = lane & 31;
    int hf = lane >> 5;
    int key0 = kvh * 2048;
    int pg = kvh * 16 + bh;

    // Q B-frags (hoisted)
    short8 qf[4];
    #pragma unroll
    for (int ks = 0; ks < 4; ++ks)
        qf[ks] = ld8(Qb + ((size_t)bh * Nn + qrow0 + q) * HDd + ks * 16 + hf * 8);

    // B-frag with ones at k=0,1 (importance augmentation)
    short8 onef = (short8)0;
    if (hf == 0) { onef[0] = (short)0x3F80; onef[1] = (short)0x3F80; }
    // all-ones A-frag (l accumulation via MFMA row-sum)
    short8 aone;
    #pragma unroll
    for (int j = 0; j < 8; ++j) aone[j] = (short)0x3F80;
    // hoisted zero C operand (keeps 16 VGPRs = 0 across the loop; kills
    // the per-tile 32x v_mov zero-init of the score accumulators)
    f32x16 fz;
    #pragma unroll
    for (int r = 0; r < 16; ++r) fz[r] = 0.f;

    // staging: lane covers LDS row base+(l>>3), slot l&7; source pre-swizzled
    int sr = lane >> 3;
    int sc = lane & 7;
    int swz = (sc ^ sr) * 8;
    const u16* kp = Kb + ((size_t)bh * Nn + key0 + wv * 16 + sr) * HDd + swz;
    const u16* vp = VTb + ((size_t)bh * HDd + wv * 16 + sr) * Nn + key0 + swz;
    size_t ib = (size_t)bbi * Nn;

    gload_lds16(kp,           (char*)Klds[0] + wv * 2048);
    gload_lds16(kp + 8 * HDd, (char*)Klds[0] + wv * 2048 + 1024);
    gload_lds16(vp,           (char*)Vlds[0] + wv * 2048);
    gload_lds16(vp + 8 * Nn,  (char*)Vlds[0] + wv * 2048 + 1024);
    kp += 64 * HDd; vp += 64;
    u32 npk0 = impPk[ib + key0 + q], npk1 = impPk[ib + key0 + 32 + q];

    f32x16 ctx[2], lacc;
    #pragma unroll
    for (int r = 0; r < 16; ++r) { ctx[0][r] = 0.f; ctx[1][r] = 0.f; lacc[r] = 0.f; }
    float m = -__builtin_inff();

    int cur = 0;
    for (int t = 0; t < 32; ++t) {
        __syncthreads();   // buf[cur] ready; buf[cur^1] free
        u32 pk0 = npk0, pk1 = npk1;
        if (t < 31) {
            gload_lds16(kp,           (char*)Klds[cur ^ 1] + wv * 2048);
            gload_lds16(kp + 8 * HDd, (char*)Klds[cur ^ 1] + wv * 2048 + 1024);
            gload_lds16(vp,           (char*)Vlds[cur ^ 1] + wv * 2048);
            gload_lds16(vp + 8 * Nn,  (char*)Vlds[cur ^ 1] + wv * 2048 + 1024);
            kp += 64 * HDd; vp += 64;
            npk0 = impPk[ib + key0 + t * 64 + 64 + q];
            npk1 = impPk[ib + key0 + t * 64 + 96 + q];
        }
        const u16* Kc = Klds[cur];
        const u16* Vc = Vlds[cur];

        // af frags: elements 0,1 = packed imp bf16 pair = one u32 word-select
        u32x4 a0w; a0w[0] = (hf == 0) ? pk0 : 0u; a0w[1] = 0u; a0w[2] = 0u; a0w[3] = 0u;
        u32x4 a1w; a1w[0] = (hf == 0) ? pk1 : 0u; a1w[1] = 0u; a1w[2] = 0u; a1w[3] = 0u;
        short8 af0 = __builtin_bit_cast(short8, a0w);
        short8 af1 = __builtin_bit_cast(short8, a1w);

        // ---- QK^T both 32-key halves; augmentation first with hoisted-zero C ----
        __builtin_amdgcn_s_setprio(1);
        f32x16 s0 = __builtin_amdgcn_mfma_f32_32x32x16_bf16(af0, onef, fz, 0, 0, 0);
        f32x16 s1 = __builtin_amdgcn_mfma_f32_32x32x16_bf16(af1, onef, fz, 0, 0, 0);
        #pragma unroll
        for (int ks = 0; ks < 4; ++ks) {
            short8 kf0 = ld8(Kc + q * 64 + (((ks * 2 + hf) ^ (q & 7)) * 8));
            short8 kf1 = ld8(Kc + (32 + q) * 64 + (((ks * 2 + hf) ^ (q & 7)) * 8));
            s0 = __builtin_amdgcn_mfma_f32_32x32x16_bf16(kf0, qf[ks], s0, 0, 0, 0);
            s1 = __builtin_amdgcn_mfma_f32_32x32x16_bf16(kf1, qf[ks], s1, 0, 0, 0);
        }
        __builtin_amdgcn_s_setprio(0);

        // ---- merged online softmax over 32 scores (exp2 domain) ----
        float a0 = max3f(s0[0], s0[1], s0[2]);
        float a1 = max3f(s0[3], s0[4], s0[5]);
        float a2 = max3f(s0[6], s0[7], s0[8]);
        float a3 = max3f(s0[9], s0[10], s0[11]);
        float a4 = max3f(s0[12], s0[13], s0[14]);
        float b0 = max3f(s1[0], s1[1], s1[2]);
        float b1 = max3f(s1[3], s1[4], s1[5]);
        float b2 = max3f(s1[6], s1[7], s1[8]);
        float b3 = max3f(s1[9], s1[10], s1[11]);
        float b4 = max3f(s1[12], s1[13], s1[14]);
        float c0 = max3f(a0, a1, a2);
        float c1 = max3f(a3, a4, s0[15]);
        float c2 = max3f(b0, b1, b2);
        float c3 = max3f(b3, b4, s1[15]);
        float tm = fmaxf(max3f(c0, c1, c2), c3);
        tm = xhalf_max(tm);
        bool nore = __all(tm <= m + 8.0f);
        if (!nore) {
            float nm = fmaxf(m, tm);
            float al = fexp2(m - nm);
            lacc[0] *= al;
            #pragma unroll
            for (int r = 0; r < 16; ++r) { ctx[0][r] *= al; ctx[1][r] *= al; }
            m = nm;
        }
        #pragma unroll
        for (int r = 0; r < 16; ++r) { s0[r] = fexp2(s0[r] - m); s1[r] = fexp2(s1[r] - m); }

        // ---- P -> bf16 B-frags in-register ----
        u32 w0[8], w1[8];
        #pragma unroll
        for (int j = 0; j < 8; ++j) {
            w0[j] = cvtpk(s0[2 * j], s0[2 * j + 1]);
            w1[j] = cvtpk(s1[2 * j], s1[2 * j + 1]);
        }
        pl32swap(w0[0], w0[2]); pl32swap(w0[1], w0[3]);
        pl32swap(w0[4], w0[6]); pl32swap(w0[5], w0[7]);
        pl32swap(w1[0], w1[2]); pl32swap(w1[1], w1[3]);
        pl32swap(w1[4], w1[6]); pl32swap(w1[5], w1[7]);
        u32x4 t00; t00[0] = w0[0]; t00[1] = w0[1]; t00[2] = w0[2]; t00[3] = w0[3];
        u32x4 t01; t01[0] = w0[4]; t01[1] = w0[5]; t01[2] = w0[6]; t01[3] = w0[7];
        u32x4 t10; t10[0] = w1[0]; t10[1] = w1[1]; t10[2] = w1[2]; t10[3] = w1[3];
        u32x4 t11; t11[0] = w1[4]; t11[1] = w1[5]; t11[2] = w1[6]; t11[3] = w1[7];
        short8 pf00 = __builtin_bit_cast(short8, t00);
        short8 pf01 = __builtin_bit_cast(short8, t01);
        short8 pf10 = __builtin_bit_cast(short8, t10);
        short8 pf11 = __builtin_bit_cast(short8, t11);

        // ---- PV + l-accumulation ----
        __builtin_amdgcn_s_setprio(1);
        lacc = __builtin_amdgcn_mfma_f32_32x32x16_bf16(aone, pf00, lacc, 0, 0, 0);
        lacc = __builtin_amdgcn_mfma_f32_32x32x16_bf16(aone, pf01, lacc, 0, 0, 0);
        lacc = __builtin_amdgcn_mfma_f32_32x32x16_bf16(aone, pf10, lacc, 0, 0, 0);
        lacc = __builtin_amdgcn_mfma_f32_32x32x16_bf16(aone, pf11, lacc, 0, 0, 0);
        #pragma unroll
        for (int dt = 0; dt < 2; ++dt) {
            int vrow = dt * 32 + q;
            const u16* vb = Vc + vrow * 64;
            int sw = vrow & 7;
            short8 vf;
            vf = ld8(vb + (((0 + hf) ^ sw) * 8));
            ctx[dt] = __builtin_amdgcn_mfma_f32_32x32x16_bf16(vf, pf00, ctx[dt], 0, 0, 0);
            vf = ld8(vb + (((2 + hf) ^ sw) * 8));
            ctx[dt] = __builtin_amdgcn_mfma_f32_32x32x16_bf16(vf, pf01, ctx[dt], 0, 0, 0);
            vf = ld8(vb + (((4 + hf) ^ sw) * 8));
            ctx[dt] = __builtin_amdgcn_mfma_f32_32x32x16_bf16(vf, pf10, ctx[dt], 0, 0, 0);
            vf = ld8(vb + (((6 + hf) ^ sw) * 8));
            ctx[dt] = __builtin_amdgcn_mfma_f32_32x32x16_bf16(vf, pf11, ctx[dt], 0, 0, 0);
        }
        __builtin_amdgcn_s_setprio(0);
        cur ^= 1;
    }

    // ---- epilogue: write unnormalized partials ----
    int qg = qrow0 + q;
    if (hf == 0) {
        pm[(size_t)pg * Nn + qg] = m;
        pl[(size_t)pg * Nn + qg] = lacc[0];
    }
    #pragma unroll
    for (int dt = 0; dt < 2; ++dt) {
        #pragma unroll
        for (int r = 0; r < 16; ++r) {
            int d = dt * 32 + (r & 3) + 8 * (r >> 2) + 4 * hf;
            pc[((size_t)pg * 64 + d) * Nn + qg] = f2bf(ctx[dt][r]);
        }
    }
}

// ---------------- merge: combine 2 KV-halves, transpose to ctx layout ----------------
__global__ __launch_bounds__(256) void merge_kernel(
        const u16* __restrict__ pc, const float* __restrict__ pm,
        const float* __restrict__ pl, u16* __restrict__ ctxOut) {
    __shared__ float trans[64][65];
    __shared__ float f0a[64], f1a[64];
    int bh = blockIdx.x >> 6;
    int q0 = (blockIdx.x & 63) * 64;
    int t = threadIdx.x;
    if (t < 64) {
        int qg = q0 + t;
        float m0 = pm[(size_t)bh * Nn + qg];
        float m1 = pm[(size_t)(16 + bh) * Nn + qg];
        float l0 = pl[(size_t)bh * Nn + qg];
        float l1 = pl[(size_t)(16 + bh) * Nn + qg];
        float M = fmaxf(m0, m1);
        float w0 = fexp2(m0 - M), w1 = fexp2(m1 - M);
        float inv = 1.0f / (l0 * w0 + l1 * w1);
        f0a[t] = w0 * inv; f1a[t] = w1 * inv;
    }
    __syncthreads();
    int wv = t >> 6, lane = t & 63;
    #pragma unroll
    for (int i = 0; i < 16; ++i) {
        int d = wv * 16 + i;
        float c0 = __uint_as_float((u32)pc[((size_t)bh * 64 + d) * Nn + q0 + lane] << 16);
        float c1 = __uint_as_float((u32)pc[((size_t)(16 + bh) * 64 + d) * Nn + q0 + lane] << 16);
        trans[lane][d] = c0 * f0a[lane] + c1 * f1a[lane];
    }
    __syncthreads();
    int q = t >> 2, dg = t & 3;
    int b = bh >> 2, h = bh & 3;
    const float* tr = &trans[q][dg * 16];
    uint4 pa, pb;
    pa.x = cvtpk(tr[0], tr[1]);  pa.y = cvtpk(tr[2], tr[3]);
    pa.z = cvtpk(tr[4], tr[5]);  pa.w = cvtpk(tr[6], tr[7]);
    pb.x = cvtpk(tr[8], tr[9]);  pb.y = cvtpk(tr[10], tr[11]);
    pb.z = cvtpk(tr[12], tr[13]); pb.w = cvtpk(tr[14], tr[15]);
    u16* op = ctxOut + ((size_t)b * Nn + q0 + q) * Dd + h * 64 + dg * 16;
    *(uint4*)op = pa;
    *(uint4*)(op + 8) = pb;
}

extern "C" void kernel_launch(void* const* d_in, const int* in_sizes, int n_in,
                              void* d_out, int out_size, void* d_ws, size_t ws_size,
                              hipStream_t stream) {
    (void)in_sizes; (void)n_in; (void)out_size; (void)ws_size;
    const float* tokens     = (const float*)d_in[0];
    const float* importance = (const float*)d_in[1];
    const float* n1w = (const float*)d_in[2];
    const float* n1b = (const float*)d_in[3];
    const float* Wq  = (const float*)d_in[4];
    const float* bq  = (const float*)d_in[5];
    const float* Wk  = (const float*)d_in[6];
    const float* bk  = (const float*)d_in[7];
    const float* Wv  = (const float*)d_in[8];
    const float* bv  = (const float*)d_in[9];
    const float* Wo  = (const float*)d_in[10];
    const float* bo  = (const float*)d_in[11];
    const float* n2w = (const float*)d_in[12];
    const float* n2b = (const float*)d_in[13];
    const float* W1  = (const float*)d_in[14];
    const float* b1  = (const float*)d_in[15];
    const float* W2  = (const float*)d_in[16];
    const float* b2  = (const float*)d_in[17];
    float* out = (float*)d_out;

    char* ws = (char*)d_ws;
    const size_t MB = (size_t)1 << 20;
    // Sequential reuse (single stream): yln reuses xln (dead after QKV GEMM);
    // hbuf reuses qb+kb (dead after attn); x2 = d_out (dead until MODE 1).
    u16* xln   = (u16*)(ws);                    // 0..8MB   (later: yln)
    u16* qb    = (u16*)(ws + 8 * MB);           // 8..16MB  (later: hbuf lo)
    u16* kb    = (u16*)(ws + 16 * MB);          // 16..24MB (later: hbuf hi)
    u16* vT    = (u16*)(ws + 24 * MB);          // 24..32MB
    u16* ctx   = (u16*)(ws + 32 * MB);          // 32..40MB
    u16* pc    = (u16*)(ws + 40 * MB);          // 40..56MB [kvh*16+bh][64 d][4096 q]
    float* pm  = (float*)(ws + 56 * MB);        // 512KB
    float* pl  = (float*)(ws + 56 * MB + 524288);
    u16* WqkvT = (u16*)(ws + 57 * MB);          // 384KB
    u16* WoT   = (u16*)(ws + 57 * MB + 393216);
    u16* W1T   = (u16*)(ws + 57 * MB + 393216 + 131072);
    u16* W2T   = (u16*)(ws + 57 * MB + 393216 + 131072 + 262144);
    u32* impPk = (u32*)(ws + 57 * MB + 393216 + 131072 + 262144 + 262144);
    u16* yln   = xln;                           // reuse (xln dead after QKV)
    u16* hbuf  = qb;                            // reuse 16MB (qb+kb dead after attn)
    float* x2  = out;                           // reuse d_out as x2 scratch

    prep_kernel<<<2112, 256, 0, stream>>>(Wq, Wk, Wv, Wo, W1, W2, importance,
                                          WqkvT, WoT, W1T, W2T, impPk);
    ln_kernel<<<4096, 256, 0, stream>>>(tokens, n1w, n1b, xln);
    gemm_bt<0, 256><<<dim3(6, 128), 256, 0, stream>>>(xln, WqkvT, bq, bk, bv,
                                                      nullptr, nullptr, qb, kb, vT);
    attn_kernel<<<1024, 256, 0, stream>>>(qb, kb, vT, impPk, pc, pm, pl);
    merge_kernel<<<1024, 256, 0, stream>>>(pc, pm, pl, ctx);
    gemm_bt<1, 256><<<dim3(2, 128), 256, 0, stream>>>(ctx, WoT, bo, nullptr, nullptr,
                                                      tokens, x2, nullptr, nullptr, nullptr);
    ln_kernel<<<4096, 256, 0, stream>>>(x2, n2w, n2b, yln);
    gemm_bt<2, 256><<<dim3(4, 128), 256, 0, stream>>>(yln, W1T, b1, nullptr, nullptr,
                                                      nullptr, nullptr, hbuf, nullptr, nullptr);
    gemm_bt<3, 512><<<dim3(2, 128), 256, 0, stream>>>(hbuf, W2T, b2, nullptr, nullptr,
                                                      x2, out, nullptr, nullptr, nullptr);
}